// Round 4
// baseline (176.942 us; speedup 1.0000x reference)
//
#include <hip/hip_runtime.h>

// Upsample 2x (nearest) + horizontal 1x16 FIR (flattened 4x4 kernel), SAME pad.
// x: (32,512,512,1) fp32, kernel: 16 fp32, out: (32,1024,1024,1) fp32.
//
// R4 = DIAGNOSTIC build: identical math, but each output float4 is stored
// STORE_REPS times (idempotent; asm memory clobber blocks dead-store elim).
// Purpose: push the kernel dispatch above the ~80us harness poison fills so
// it lands in the rocprof top-5 and we finally see its own counters
// (dur, FETCH_SIZE -> RFO?, WRITE_SIZE, VALUBusy, Occupancy). The marginal
// store bandwidth = 402 MB / (D4x - D1x) calibrates the store path, and
// dur_us - D4x pins the fixed harness overhead. R5 reverts STORE_REPS to 1.
//
// Math structure (verified R1/R3, absmax 0.03):
//  - horizontal-only conv + row-duplicated upsample -> out rows 2g,2g+1
//    identical: compute once, store twice.
//  - up[p]=x[p>>1] collapses 16-tap FIR to 9-tap (even cols) / 8-tap (odd)
//    polyphase on x; 4-wide zero halo makes boundaries exact.

#define W_IN   512
#define H_IN   512
#define NB     32
#define W_OUT  1024
#define TILE_R 8
#define ROWSTRIDE 520   // 512 data + 4 zero halo each side
#define STORE_REPS 4    // DIAGNOSTIC: 4x writes => kernel > 80us => visible in top-5

__global__ __launch_bounds__(256) void upsample_blur_kernel(
    const float* __restrict__ x,
    const float* __restrict__ kern,
    float* __restrict__ out)
{
    __shared__ float smem[TILE_R * ROWSTRIDE];

    const int t  = threadIdx.x;                 // 0..255
    const int g0 = blockIdx.x * TILE_R;         // global input row base

    // zero halos: 8 rows x 8 floats = 64 lanes
    if (t < TILE_R * 8) {
        const int rr = t >> 3;
        const int p  = t & 7;
        smem[rr * ROWSTRIDE + ((p < 4) ? p : 512 + p)] = 0.0f;
    }

    // stage TILE_R rows (16 KB) via float4: 1024 float4 units, 4 per thread
    const float4* __restrict__ src4 =
        reinterpret_cast<const float4*>(x + (size_t)g0 * W_IN);
#pragma unroll
    for (int i = 0; i < 4; ++i) {
        const int idx = t + 256 * i;            // 0..1023
        const int rr  = idx >> 7;
        const int c4  = idx & 127;
        const float4 v = src4[idx];
        *reinterpret_cast<float4*>(&smem[rr * ROWSTRIDE + 4 + c4 * 4]) = v;
    }

    // collapsed polyphase weights (uniform)
    float kf[16];
#pragma unroll
    for (int i = 0; i < 16; ++i) kf[i] = kern[i];
    float we[9], wo[8];
    we[0] = kf[0];
#pragma unroll
    for (int i = 0; i < 7; ++i) we[i + 1] = kf[2 * i + 1] + kf[2 * i + 2];
    we[8] = kf[15];
#pragma unroll
    for (int i = 0; i < 8; ++i) wo[i] = kf[2 * i] + kf[2 * i + 1];

    __syncthreads();

#pragma unroll
    for (int rr = 0; rr < TILE_R; ++rr) {
        const float2* rowp =
            reinterpret_cast<const float2*>(&smem[rr * ROWSTRIDE]);
        const float2 p0 = rowp[t];
        const float2 p1 = rowp[t + 1];
        const float2 p2 = rowp[t + 2];
        const float2 p3 = rowp[t + 3];
        const float2 p4 = rowp[t + 4];
        float v[10];
        v[0] = p0.x; v[1] = p0.y; v[2] = p1.x; v[3] = p1.y; v[4] = p2.x;
        v[5] = p2.y; v[6] = p3.x; v[7] = p3.y; v[8] = p4.x; v[9] = p4.y;

        float o0 = 0.f, o1 = 0.f, o2 = 0.f, o3 = 0.f;
#pragma unroll
        for (int j = 0; j < 9; ++j) o0 += we[j] * v[j];       // w=4t   (even)
#pragma unroll
        for (int j = 0; j < 8; ++j) o1 += wo[j] * v[j + 1];   // w=4t+1 (odd)
#pragma unroll
        for (int j = 0; j < 9; ++j) o2 += we[j] * v[j + 1];   // w=4t+2 (even)
#pragma unroll
        for (int j = 0; j < 8; ++j) o3 += wo[j] * v[j + 2];   // w=4t+3 (odd)

        const float4 o = make_float4(o0, o1, o2, o3);
        const size_t g = (size_t)(g0 + rr);
        float* orow = out + 2 * g * (size_t)W_OUT;

        // DIAGNOSTIC: repeat the (idempotent) stores STORE_REPS times.
        // Memory clobber prevents the compiler eliding duplicate stores.
        for (int rep = 0; rep < STORE_REPS; ++rep) {
            reinterpret_cast<float4*>(orow)[t] = o;          // row 2g
            reinterpret_cast<float4*>(orow + W_OUT)[t] = o;  // row 2g+1
            __asm__ volatile("" ::: "memory");
        }
    }
}

extern "C" void kernel_launch(void* const* d_in, const int* in_sizes, int n_in,
                              void* d_out, int out_size, void* d_ws, size_t ws_size,
                              hipStream_t stream) {
    const float* x    = (const float*)d_in[0];
    const float* kern = (const float*)d_in[1];
    float* out        = (float*)d_out;

    const int numBlocks = NB * H_IN / TILE_R;   // 2048 blocks, 8 rows each
    upsample_blur_kernel<<<numBlocks, 256, 0, stream>>>(x, kern, out);
}

// Round 5
// 157.024 us; speedup vs baseline: 1.1269x; 1.1269x over previous
//
#include <hip/hip_runtime.h>

// Upsample 2x (nearest) + horizontal 1x16 FIR (flattened 4x4 kernel), SAME pad.
// x: (32,512,512,1) fp32, kernel: 16 fp32, out: (32,1024,1024,1) fp32.
//
// R5 = R1 one-row-per-block structure (16384 blocks — measured best: the
// 8-row tile of R3/R4 regressed ~7us) + nontemporal float4 stores (output is
// write-once; NT avoids dirtying L2 lines that would re-drain while the
// harness's 512MiB/134MB poison fills are still draining).
//
// Math structure (verified, absmax 0.03):
//  - conv is horizontal-only, upsampled rows 2r,2r+1 identical ->
//    output rows 2r,2r+1 identical: compute once, store twice.
//  - up[p]=x[p>>1] collapses the 16-tap FIR to 9-tap (even cols) / 8-tap
//    (odd cols) polyphase on x; 4-wide zero halo makes boundaries exact.
//
// Timing note: dur_us is composite (restore d_in 67MB + poison d_out 134MB +
// poison d_ws 512MiB + kernel 168MB ≈ 904MB mandatory traffic ≈ 140us floor
// at the fills' 6.9 TB/s). Kernel-attributable slice ≈ 46us in R1.

#define W_IN  512
#define H_IN  512
#define NB    32
#define W_OUT 1024

typedef float vf4 __attribute__((ext_vector_type(4)));

__global__ __launch_bounds__(256) void upsample_blur_kernel(
    const float* __restrict__ x,
    const float* __restrict__ kern,
    float* __restrict__ out)
{
    // LDS row: indices 0..519; data at [4..515], zero halo [0..3],[516..519]
    __shared__ float row[520];

    const int rowIdx = blockIdx.x;          // n*512 + r
    const int t = threadIdx.x;              // 0..255

    // zero halos
    if (t < 8) {
        row[(t < 4) ? t : (512 + t)] = 0.0f;   // 0..3, 516..519
    }

    // stage input row (512 floats) into LDS at offset 4 (float2, coalesced)
    const float* xrow = x + (size_t)rowIdx * W_IN;
    reinterpret_cast<float2*>(row + 4)[t] = reinterpret_cast<const float2*>(xrow)[t];

    // collapsed polyphase weights (uniform -> scalar loads)
    float kf[16];
#pragma unroll
    for (int i = 0; i < 16; ++i) kf[i] = kern[i];
    float we[9], wo[8];
    we[0] = kf[0];
#pragma unroll
    for (int i = 0; i < 7; ++i) we[i + 1] = kf[2 * i + 1] + kf[2 * i + 2];
    we[8] = kf[15];
#pragma unroll
    for (int i = 0; i < 8; ++i) wo[i] = kf[2 * i] + kf[2 * i + 1];

    __syncthreads();

    // thread t computes output cols w = 4t..4t+3 (u = 2t, 2t+1);
    // needs row[2t .. 2t+9] -> five ds_read_b64 (stride-2: 2-way, free)
    const float2* rowp = reinterpret_cast<const float2*>(row);
    const float2 p0 = rowp[t];
    const float2 p1 = rowp[t + 1];
    const float2 p2 = rowp[t + 2];
    const float2 p3 = rowp[t + 3];
    const float2 p4 = rowp[t + 4];
    float v[10];
    v[0] = p0.x; v[1] = p0.y; v[2] = p1.x; v[3] = p1.y; v[4] = p2.x;
    v[5] = p2.y; v[6] = p3.x; v[7] = p3.y; v[8] = p4.x; v[9] = p4.y;

    float o0 = 0.f, o1 = 0.f, o2 = 0.f, o3 = 0.f;
#pragma unroll
    for (int j = 0; j < 9; ++j) o0 += we[j] * v[j];       // w=4t   (even)
#pragma unroll
    for (int j = 0; j < 8; ++j) o1 += wo[j] * v[j + 1];   // w=4t+1 (odd)
#pragma unroll
    for (int j = 0; j < 9; ++j) o2 += we[j] * v[j + 1];   // w=4t+2 (even)
#pragma unroll
    for (int j = 0; j < 8; ++j) o3 += wo[j] * v[j + 2];   // w=4t+3 (odd)

    vf4 o; o.x = o0; o.y = o1; o.z = o2; o.w = o3;
    const size_t outRowBase = (size_t)rowIdx * 2 * W_OUT;
    __builtin_nontemporal_store(o, reinterpret_cast<vf4*>(out + outRowBase) + t);
    __builtin_nontemporal_store(o, reinterpret_cast<vf4*>(out + outRowBase + W_OUT) + t);
}

extern "C" void kernel_launch(void* const* d_in, const int* in_sizes, int n_in,
                              void* d_out, int out_size, void* d_ws, size_t ws_size,
                              hipStream_t stream) {
    const float* x    = (const float*)d_in[0];
    const float* kern = (const float*)d_in[1];
    float* out        = (float*)d_out;

    const int numRows = NB * H_IN;   // 16384 blocks, one input row each
    upsample_blur_kernel<<<numRows, 256, 0, stream>>>(x, kern, out);
}

// Round 6
// 154.261 us; speedup vs baseline: 1.1470x; 1.0179x over previous
//
#include <hip/hip_runtime.h>

// Upsample 2x (nearest) + horizontal 1x16 FIR (flattened 4x4 kernel), SAME pad.
// x: (32,512,512,1) fp32, kernel: 16 fp32, out: (32,1024,1024,1) fp32.
//
// FINAL = R1 structure (measured best across 4 variants):
//   one input row per block (16384 blocks x 256 thr), plain float4 stores.
//   Measured: 154.2us composite. Variants: +NT stores 157.0, 8-row tile+NT
//   161.6, 8-row+4x-store diag 176.9 -> one-row/plain wins; NT neutral
//   (poison-fill noise is +/-4us round-to-round).
//
// Math structure (verified, absmax 0.03125 vs 0.1875 threshold):
//  - conv is horizontal-only and upsampled rows 2r,2r+1 are identical
//    -> output rows 2r,2r+1 identical: compute once, store twice.
//  - up[p]=x[p>>1] collapses the 16-tap FIR to a 9-tap (even out cols) /
//    8-tap (odd out cols) polyphase filter directly on x; zero-padding x by
//    4 each side makes the collapsed form exact at boundaries.
//
// Roofline note: kernel mandatory traffic = 33.5MB read + 134MB write
// (~25us at 6.7TB/s). dur_us is composite with ~740MB of harness poison/
// restore traffic (~135-140us floor at the fills' demonstrated 6.9TB/s);
// measured 154us = ~90% of that composite ceiling.

#define W_IN  512
#define H_IN  512
#define NB    32
#define W_OUT 1024

__global__ __launch_bounds__(256) void upsample_blur_kernel(
    const float* __restrict__ x,
    const float* __restrict__ kern,
    float* __restrict__ out)
{
    // LDS row: indices 0..519; data at [4..515], zero halo [0..3],[516..519]
    __shared__ float row[520];

    const int rowIdx = blockIdx.x;          // n*512 + r
    const int t = threadIdx.x;              // 0..255

    // zero halos
    if (t < 8) {
        row[(t < 4) ? t : (512 + t)] = 0.0f;   // 0..3, 516..519
    }

    // stage input row (512 floats) into LDS at offset 4 (float2, coalesced)
    const float* xrow = x + (size_t)rowIdx * W_IN;
    reinterpret_cast<float2*>(row + 4)[t] = reinterpret_cast<const float2*>(xrow)[t];

    // collapsed polyphase weights (uniform -> scalar loads)
    float kf[16];
#pragma unroll
    for (int i = 0; i < 16; ++i) kf[i] = kern[i];
    float we[9], wo[8];
    we[0] = kf[0];
#pragma unroll
    for (int i = 0; i < 7; ++i) we[i + 1] = kf[2 * i + 1] + kf[2 * i + 2];
    we[8] = kf[15];
#pragma unroll
    for (int i = 0; i < 8; ++i) wo[i] = kf[2 * i] + kf[2 * i + 1];

    __syncthreads();

    // thread t computes output cols w = 4t..4t+3 (u = 2t, 2t+1);
    // needs row[2t .. 2t+9] -> five ds_read_b64 (stride-2: 2-way, free)
    const float2* rowp = reinterpret_cast<const float2*>(row);
    const float2 p0 = rowp[t];
    const float2 p1 = rowp[t + 1];
    const float2 p2 = rowp[t + 2];
    const float2 p3 = rowp[t + 3];
    const float2 p4 = rowp[t + 4];
    float v[10];
    v[0] = p0.x; v[1] = p0.y; v[2] = p1.x; v[3] = p1.y; v[4] = p2.x;
    v[5] = p2.y; v[6] = p3.x; v[7] = p3.y; v[8] = p4.x; v[9] = p4.y;

    float o0 = 0.f, o1 = 0.f, o2 = 0.f, o3 = 0.f;
#pragma unroll
    for (int j = 0; j < 9; ++j) o0 += we[j] * v[j];       // w=4t   (even)
#pragma unroll
    for (int j = 0; j < 8; ++j) o1 += wo[j] * v[j + 1];   // w=4t+1 (odd)
#pragma unroll
    for (int j = 0; j < 9; ++j) o2 += we[j] * v[j + 1];   // w=4t+2 (even)
#pragma unroll
    for (int j = 0; j < 8; ++j) o3 += wo[j] * v[j + 2];   // w=4t+3 (odd)

    const float4 o = make_float4(o0, o1, o2, o3);
    const size_t outRowBase = (size_t)rowIdx * 2 * W_OUT;
    reinterpret_cast<float4*>(out + outRowBase)[t] = o;          // row 2r
    reinterpret_cast<float4*>(out + outRowBase + W_OUT)[t] = o;  // row 2r+1
}

extern "C" void kernel_launch(void* const* d_in, const int* in_sizes, int n_in,
                              void* d_out, int out_size, void* d_ws, size_t ws_size,
                              hipStream_t stream) {
    const float* x    = (const float*)d_in[0];
    const float* kern = (const float*)d_in[1];
    float* out        = (float*)d_out;

    const int numRows = NB * H_IN;   // 16384 blocks, one input row each
    upsample_blur_kernel<<<numRows, 256, 0, stream>>>(x, kern, out);
}